// Round 7
// baseline (2231.861 us; speedup 1.0000x reference)
//
#include <hip/hip_runtime.h>
#include <stdint.h>

typedef int v4i __attribute__((ext_vector_type(4)));

// quantized_bits(6,0): returns INTEGER level in [-32,31] (value = level/32)
__device__ __forceinline__ float qlevel(float x) {
  float p = rintf(x * 32.0f);            // v_rndne: round half-to-even == jnp.round
  return fminf(fmaxf(p, -32.0f), 31.0f);
}

__device__ __forceinline__ int8_t qrelu_level(float p) {
  // p = 64*h already; quantized_relu level = clip(round(p), 0, 63)
  int q = (int)rintf(p);
  q = q < 0 ? 0 : (q > 63 ? 63 : q);
  return (int8_t)q;
}

__device__ __forceinline__ void async16(const void* g, void* l) {
  __builtin_amdgcn_global_load_lds(
      (const __attribute__((address_space(1))) void*)g,
      (__attribute__((address_space(3))) void*)l, 16, 0, 0);
}

// ---------------------------------------------------------------- weight quant
__global__ __launch_bounds__(256) void quant_w0_k(const float* __restrict__ W,
                                                  int8_t* __restrict__ wq) {
  int i = blockIdx.x * 256 + threadIdx.x;  // over float4, 32768 total
  float4 v = ((const float4*)W)[i];
  char4 c;
  c.x = (int8_t)(int)qlevel(v.x);
  c.y = (int8_t)(int)qlevel(v.y);
  c.z = (int8_t)(int)qlevel(v.z);
  c.w = (int8_t)(int)qlevel(v.w);
  ((char4*)wq)[i] = c;
}

// Quantize + transpose, direct: W (K x N fp32) -> wt (N x K int8).
__global__ __launch_bounds__(256) void quantT_k(const float* __restrict__ W,
                                                int8_t* __restrict__ wt,
                                                int K, int N) {
  const int t = threadIdx.x;
  const int l = t & 63;
  const int kc = t >> 6;                       // 0..3
  const int k0 = blockIdx.y * 64 + kc * 16;
  const int n = blockIdx.x * 64 + l;
  union { int8_t b[16]; int4 v; } u;
#pragma unroll
  for (int j = 0; j < 16; ++j)
    u.b[j] = (int8_t)(int)qlevel(W[(size_t)(k0 + j) * N + n]);
  *(int4*)&wt[(size_t)n * K + k0] = u.v;
}

// Bias quant: store integer level as float (value = level/32).
__global__ __launch_bounds__(256) void quant_bias_k(
    const float* __restrict__ b0, const float* __restrict__ b1,
    const float* __restrict__ b2, const float* __restrict__ b3,
    float* __restrict__ o0, float* __restrict__ o1,
    float* __restrict__ o2, float* __restrict__ o3) {
  int i = blockIdx.x * 256 + threadIdx.x;  // grid 16 -> 4096 threads
  if (i < 1024) o0[i] = qlevel(b0[i]);
  if (i < 2048) o1[i] = qlevel(b1[i]);
  o2[i] = qlevel(b2[i]);
  o3[i] = qlevel(b3[i]);
}

// ---------------------------------------------------------------- layer 0
// M=8192 K=128 N=1024. 64x64 block tile, 4x4 register block per thread.
__global__ __launch_bounds__(256) void layer0_k(const float* __restrict__ x,
                                                const int8_t* __restrict__ w0q,
                                                const float* __restrict__ bint,
                                                int8_t* __restrict__ a1) {
  const int K = 128, N = 1024;
  __shared__ float xs[64][132];      // +4 pad: conflict-free, float4-aligned
  __shared__ int8_t wsm[128][64];
  const int tid = threadIdx.x;
  const int m0 = blockIdx.y * 64;
  const int n0 = blockIdx.x * 64;
#pragma unroll
  for (int i = 0; i < 8; ++i) {      // stage x tile: 64x128 fp32
    int idx = tid + 256 * i;
    int row = idx >> 5, c4 = idx & 31;
    float4 v = *(const float4*)(x + (size_t)(m0 + row) * K + c4 * 4);
    *(float4*)&xs[row][c4 * 4] = v;
  }
#pragma unroll
  for (int i = 0; i < 8; ++i) {      // stage w tile: 128x64 int8
    int idx = tid + 256 * i;
    int k = idx >> 4, c4 = idx & 15;
    *(int*)&wsm[k][c4 * 4] = *(const int*)(w0q + (size_t)k * N + n0 + c4 * 4);
  }
  __syncthreads();
  const int ty = tid >> 4, tx = tid & 15;
  float acc[4][4] = {};
  for (int k4 = 0; k4 < K; k4 += 4) {
    float xr[4][4];
#pragma unroll
    for (int i = 0; i < 4; ++i) {
      float4 v = *(const float4*)&xs[ty * 4 + i][k4];
      xr[i][0] = v.x; xr[i][1] = v.y; xr[i][2] = v.z; xr[i][3] = v.w;
    }
#pragma unroll
    for (int kk = 0; kk < 4; ++kk) {
      char4 cv = *(const char4*)&wsm[k4 + kk][tx * 4];
      float w0 = (float)cv.x, w1 = (float)cv.y, w2 = (float)cv.z, w3 = (float)cv.w;
#pragma unroll
      for (int i = 0; i < 4; ++i) {
        acc[i][0] = fmaf(xr[i][kk], w0, acc[i][0]);
        acc[i][1] = fmaf(xr[i][kk], w1, acc[i][1]);
        acc[i][2] = fmaf(xr[i][kk], w2, acc[i][2]);
        acc[i][3] = fmaf(xr[i][kk], w3, acc[i][3]);
      }
    }
  }
  const int n = n0 + tx * 4;
  float b0v = 2.0f * bint[n + 0], b1v = 2.0f * bint[n + 1];
  float b2v = 2.0f * bint[n + 2], b3v = 2.0f * bint[n + 3];
#pragma unroll
  for (int i = 0; i < 4; ++i) {
    int m = m0 + ty * 4 + i;
    char4 o;
    o.x = qrelu_level(2.0f * acc[i][0] + b0v);
    o.y = qrelu_level(2.0f * acc[i][1] + b1v);
    o.z = qrelu_level(2.0f * acc[i][2] + b2v);
    o.w = qrelu_level(2.0f * acc[i][3] + b3v);
    *(char4*)&a1[(size_t)m * 1024 + n] = o;
  }
}

// ---------------------------------------------------------------- int8 GEMM
// C = A(MxK,int8) * BT(NxK,int8)^T.
//
// Round-10: back to the proven 256x256/8-wave fine-phase schedule (best run:
// 144 us, MfmaUtil 40, VALU 19) with ONE change: 2 LDS buffers (64 KB) so
// TWO blocks co-reside per CU.
//
// Post-mortem driving this: the 128x128/3-block round REGRESSED (194 us,
// MfmaUtil 30, VALU 52): occupancy rose (21->29) but halving the tile halved
// the per-phase MFMA cluster while keeping per-phase overhead constant ->
// VALU issue (52%) choked MFMA issue (shared SIMD issue slots). TLP only
// pays if added waves keep the good MFMA:VALU mix -> keep 256^2 geometry
// (mix 1306:515 cyc per SIMD-iter) and desync across 2 blocks instead.
//
// Stage depth 1: all 4 loads of tile t+1 issue at Ph1 of iter t into buf
// 1-p; single vmcnt(0) sits AFTER Ph2's MFMA cluster (in-flight ~900-1100
// cyc -> covers L2 fully, HBM mostly). Buffer rotation t&1 (no %3 chains).
// Overwrite safety: buf 1-p last read in iter t-1 (lgkm-retired before its
// mid barrier); stage issues after iter t-1's final barrier.
//
// LDS bank-swizzle (kept, measured conflict-free): chunk kc of row `row`
// stored at position p = (kc + (row>>1)) & 3; fragment reads p = (quad+(r>>1))&3.
//
// FINAL=false: out int8 = clip(round(C/32 + 2*bint),0,63)   (relu-quant level)
// FINAL=true : out fp32 = C/2048 + bint/32
template <bool FINAL>
__global__ __launch_bounds__(512, 4) void gemm_i8(const int8_t* __restrict__ A,
                                                  const int8_t* __restrict__ BT,
                                                  const float* __restrict__ bint,
                                                  void* __restrict__ outp,
                                                  int M, int N, int K) {
  __shared__ __align__(16) int8_t ldsA[2][256 * 64];
  __shared__ __align__(16) int8_t ldsB[2][256 * 64];
  const int tid = threadIdx.x;
  const int wid = tid >> 6;                 // 0..7
  const int lane = tid & 63;
  const int wm = wid >> 2, wn = wid & 3;    // 2 (M) x 4 (N) waves
  const int quad = lane >> 4, r = lane & 15;
  const int m0 = blockIdx.y * 256, n0 = blockIdx.x * 256;

  const int8_t* Ab = A + (size_t)m0 * K;
  const int8_t* Bb = BT + (size_t)n0 * K;

  // staging geometry (swizzled): thread covers LDS chunks tid and tid+512;
  // chunk c -> row = c>>2, pos p = c&3; fetch global chunk kc = (p-(row>>1))&3.
  const int srow = tid >> 2;                // 0..127 (second async: +128)
  const int sp = tid & 3;
  const int skc = (sp - (srow >> 1)) & 3;   // same for row+128
  const int8_t* gA0 = Ab + (size_t)srow * K + skc * 16;
  const int8_t* gA1 = Ab + (size_t)(srow + 128) * K + skc * 16;
  const int8_t* gB0 = Bb + (size_t)srow * K + skc * 16;
  const int8_t* gB1 = Bb + (size_t)(srow + 128) * K + skc * 16;
  const int ldsOff0 = (wid * 64) * 16;          // wave-uniform; HW adds lane*16
  const int ldsOff1 = (512 + wid * 64) * 16;

  // fragment-read position within a row's 64B
  const int pfrag = (quad + (r >> 1)) & 3;

  v4i acc[8][4] = {};

#define STAGE(buf, kt)                                \
  do {                                                \
    async16(gA0 + (kt) * 64, &ldsA[buf][ldsOff0]);    \
    async16(gA1 + (kt) * 64, &ldsA[buf][ldsOff1]);    \
    async16(gB0 + (kt) * 64, &ldsB[buf][ldsOff0]);    \
    async16(gB1 + (kt) * 64, &ldsB[buf][ldsOff1]);    \
  } while (0)

  // One K-tile = two template-shaped phases. doStage/vmN fold at expansion.
  // Ph1: 8 ds_read + (stage 4 loads for tile kt into buf 1-p) + 16 MFMA.
  // Ph2: 4 ds_read + 16 MFMA + [vmcnt(0) after MFMA, before final barrier].
#define ITER(p, kt, doStage, vmN)                                             \
  do {                                                                        \
    v4i bf[4], af[4];                                                         \
    const int8_t* La_ = &ldsA[p][0];                                          \
    const int8_t* Lb_ = &ldsB[p][0];                                          \
    _Pragma("unroll")                                                         \
    for (int nt = 0; nt < 4; ++nt)                                            \
      bf[nt] = *(const v4i*)&Lb_[(wn * 64 + nt * 16 + r) * 64 + pfrag * 16];  \
    _Pragma("unroll")                                                         \
    for (int mt = 0; mt < 4; ++mt)                                            \
      af[mt] = *(const v4i*)&La_[(wm * 128 + mt * 16 + r) * 64 + pfrag * 16]; \
    if (doStage) STAGE(1 - (p), kt);                                          \
    __builtin_amdgcn_s_barrier();                                             \
    asm volatile("s_waitcnt lgkmcnt(0)" ::: "memory");                        \
    __builtin_amdgcn_sched_barrier(0);                                        \
    __builtin_amdgcn_s_setprio(1);                                            \
    _Pragma("unroll")                                                         \
    for (int mt = 0; mt < 4; ++mt)                                            \
      _Pragma("unroll")                                                       \
      for (int nt = 0; nt < 4; ++nt)                                          \
        acc[mt][nt] = __builtin_amdgcn_mfma_i32_16x16x64_i8(                  \
            af[mt], bf[nt], acc[mt][nt], 0, 0, 0);                            \
    __builtin_amdgcn_s_setprio(0);                                            \
    __builtin_amdgcn_s_barrier();                                             \
    _Pragma("unroll")                                                         \
    for (int mt = 0; mt < 4; ++mt)                                            \
      af[mt] = *(const v4i*)&La_[(wm * 128 + 64 + mt * 16 + r) * 64 +         \
                                 pfrag * 16];                                 \
    __builtin_amdgcn_s_barrier();                                             \
    asm volatile("s_waitcnt lgkmcnt(0)" ::: "memory");                        \
    __builtin_amdgcn_sched_barrier(0);                                        \
    __builtin_amdgcn_s_setprio(1);                                            \
    _Pragma("unroll")                                                         \
    for (int mt = 0; mt < 4; ++mt)                                            \
      _Pragma("unroll")                                                       \
      for (int nt = 0; nt < 4; ++nt)                                          \
        acc[4 + mt][nt] = __builtin_amdgcn_mfma_i32_16x16x64_i8(              \
            af[mt], bf[nt], acc[4 + mt][nt], 0, 0, 0);                        \
    __builtin_amdgcn_s_setprio(0);                                            \
    if (vmN == 0) asm volatile("s_waitcnt vmcnt(0)" ::: "memory");            \
    __builtin_amdgcn_s_barrier();                                             \
  } while (0)

  const int NT = K >> 6;  // 16 / 32 / 64

  // prologue: stage tile 0 into buf 0, drain, publish
  STAGE(0, 0);
  asm volatile("s_waitcnt vmcnt(0)" ::: "memory");
  __builtin_amdgcn_s_barrier();

  for (int t = 0; t < NT - 1; ++t) {
    ITER(t & 1, t + 1, true, 0);      // compute buf t&1, stage t+1 into other
  }
  ITER((NT - 1) & 1, 0, false, -1);   // last tile: nothing outstanding

#undef ITER
#undef STAGE

  const int mbase = m0 + wm * 128;
  const int nbase = n0 + wn * 64;
  if (FINAL) {
    float* out = (float*)outp;
#pragma unroll
    for (int nt = 0; nt < 4; ++nt) {
      int n = nbase + nt * 16 + r;
      float bq = bint[n] * 0.03125f;
#pragma unroll
      for (int mt = 0; mt < 8; ++mt)
#pragma unroll
        for (int g = 0; g < 4; ++g) {
          int m = mbase + mt * 16 + quad * 4 + g;
          out[(size_t)m * N + n] = (float)acc[mt][nt][g] * (1.0f / 2048.0f) + bq;
        }
    }
  } else {
    int8_t* out = (int8_t*)outp;
#pragma unroll
    for (int nt = 0; nt < 4; ++nt) {
      int n = nbase + nt * 16 + r;
      float b2 = 2.0f * bint[n];
#pragma unroll
      for (int mt = 0; mt < 8; ++mt)
#pragma unroll
        for (int g = 0; g < 4; ++g) {
          int m = mbase + mt * 16 + quad * 4 + g;
          // p = C/32 + 2*bint exactly representable in fp32 -> exact half-even ties
          out[(size_t)m * N + n] =
              qrelu_level((float)acc[mt][nt][g] * 0.03125f + b2);
        }
    }
  }
}

// ---------------------------------------------------------------- launch
extern "C" void kernel_launch(void* const* d_in, const int* in_sizes, int n_in,
                              void* d_out, int out_size, void* d_ws, size_t ws_size,
                              hipStream_t stream) {
  const float* x  = (const float*)d_in[0];
  const float* W0 = (const float*)d_in[1];
  const float* b0 = (const float*)d_in[2];
  const float* W1 = (const float*)d_in[3];
  const float* b1 = (const float*)d_in[4];
  const float* W2 = (const float*)d_in[5];
  const float* b2 = (const float*)d_in[6];
  const float* W3 = (const float*)d_in[7];
  const float* b3 = (const float*)d_in[8];

  uint8_t* ws = (uint8_t*)d_ws;
  int8_t* wq0 = (int8_t*)(ws + 0);          // 128x1024 int8   (K-major)
  int8_t* wt1 = (int8_t*)(ws + 131072);     // 2048x1024 int8  (N x K)
  int8_t* wt2 = (int8_t*)(ws + 2228224);    // 4096x2048
  int8_t* wt3 = (int8_t*)(ws + 10616832);   // 4096x4096
  float*  bq0 = (float*)(ws + 27394048);    // 1024 f32 (integer levels)
  float*  bq1 = (float*)(ws + 27398144);    // 2048
  float*  bq2 = (float*)(ws + 27406336);    // 4096
  float*  bq3 = (float*)(ws + 27422720);    // 4096
  int8_t* a1  = (int8_t*)(ws + 27439104);   // 8192x1024 int8
  int8_t* a2  = (int8_t*)(ws + 35827712);   // 8192x2048
  int8_t* a3  = (int8_t*)(ws + 52604928);   // 8192x4096  (ends at 86159360 B)

  quant_w0_k<<<128, 256, 0, stream>>>(W0, wq0);
  quantT_k<<<dim3(2048 / 64, 1024 / 64), 256, 0, stream>>>(W1, wt1, 1024, 2048);
  quantT_k<<<dim3(4096 / 64, 2048 / 64), 256, 0, stream>>>(W2, wt2, 2048, 4096);
  quantT_k<<<dim3(4096 / 64, 4096 / 64), 256, 0, stream>>>(W3, wt3, 4096, 4096);
  quant_bias_k<<<16, 256, 0, stream>>>(b0, b1, b2, b3, bq0, bq1, bq2, bq3);
  layer0_k<<<dim3(16, 128), 256, 0, stream>>>(x, wq0, bq0, a1);
  gemm_i8<false><<<dim3(2048 / 256, 8192 / 256), 512, 0, stream>>>(
      a1, wt1, bq1, a2, 8192, 2048, 1024);
  gemm_i8<false><<<dim3(4096 / 256, 8192 / 256), 512, 0, stream>>>(
      a2, wt2, bq2, a3, 8192, 4096, 2048);
  gemm_i8<true><<<dim3(4096 / 256, 8192 / 256), 512, 0, stream>>>(
      a3, wt3, bq3, d_out, 8192, 4096, 4096);
}

// Round 8
// 459.781 us; speedup vs baseline: 4.8542x; 4.8542x over previous
//
#include <hip/hip_runtime.h>
#include <stdint.h>

typedef int v4i __attribute__((ext_vector_type(4)));

// quantized_bits(6,0): returns INTEGER level in [-32,31] (value = level/32)
__device__ __forceinline__ float qlevel(float x) {
  float p = rintf(x * 32.0f);            // v_rndne: round half-to-even == jnp.round
  return fminf(fmaxf(p, -32.0f), 31.0f);
}

__device__ __forceinline__ int8_t qrelu_level(float p) {
  // p = 64*h already; quantized_relu level = clip(round(p), 0, 63)
  int q = (int)rintf(p);
  q = q < 0 ? 0 : (q > 63 ? 63 : q);
  return (int8_t)q;
}

__device__ __forceinline__ void async16(const void* g, void* l) {
  __builtin_amdgcn_global_load_lds(
      (const __attribute__((address_space(1))) void*)g,
      (__attribute__((address_space(3))) void*)l, 16, 0, 0);
}

// ---------------------------------------------------------------- weight quant
__global__ __launch_bounds__(256) void quant_w0_k(const float* __restrict__ W,
                                                  int8_t* __restrict__ wq) {
  int i = blockIdx.x * 256 + threadIdx.x;  // over float4, 32768 total
  float4 v = ((const float4*)W)[i];
  char4 c;
  c.x = (int8_t)(int)qlevel(v.x);
  c.y = (int8_t)(int)qlevel(v.y);
  c.z = (int8_t)(int)qlevel(v.z);
  c.w = (int8_t)(int)qlevel(v.w);
  ((char4*)wq)[i] = c;
}

// Quantize + transpose, direct: W (K x N fp32) -> wt (N x K int8).
__global__ __launch_bounds__(256) void quantT_k(const float* __restrict__ W,
                                                int8_t* __restrict__ wt,
                                                int K, int N) {
  const int t = threadIdx.x;
  const int l = t & 63;
  const int kc = t >> 6;                       // 0..3
  const int k0 = blockIdx.y * 64 + kc * 16;
  const int n = blockIdx.x * 64 + l;
  union { int8_t b[16]; int4 v; } u;
#pragma unroll
  for (int j = 0; j < 16; ++j)
    u.b[j] = (int8_t)(int)qlevel(W[(size_t)(k0 + j) * N + n]);
  *(int4*)&wt[(size_t)n * K + k0] = u.v;
}

// Bias quant: store integer level as float (value = level/32).
__global__ __launch_bounds__(256) void quant_bias_k(
    const float* __restrict__ b0, const float* __restrict__ b1,
    const float* __restrict__ b2, const float* __restrict__ b3,
    float* __restrict__ o0, float* __restrict__ o1,
    float* __restrict__ o2, float* __restrict__ o3) {
  int i = blockIdx.x * 256 + threadIdx.x;  // grid 16 -> 4096 threads
  if (i < 1024) o0[i] = qlevel(b0[i]);
  if (i < 2048) o1[i] = qlevel(b1[i]);
  o2[i] = qlevel(b2[i]);
  o3[i] = qlevel(b3[i]);
}

// ---------------------------------------------------------------- layer 0
// M=8192 K=128 N=1024. 64x64 block tile, 4x4 register block per thread.
__global__ __launch_bounds__(256) void layer0_k(const float* __restrict__ x,
                                                const int8_t* __restrict__ w0q,
                                                const float* __restrict__ bint,
                                                int8_t* __restrict__ a1) {
  const int K = 128, N = 1024;
  __shared__ float xs[64][132];      // +4 pad: conflict-free, float4-aligned
  __shared__ int8_t wsm[128][64];
  const int tid = threadIdx.x;
  const int m0 = blockIdx.y * 64;
  const int n0 = blockIdx.x * 64;
#pragma unroll
  for (int i = 0; i < 8; ++i) {      // stage x tile: 64x128 fp32
    int idx = tid + 256 * i;
    int row = idx >> 5, c4 = idx & 31;
    float4 v = *(const float4*)(x + (size_t)(m0 + row) * K + c4 * 4);
    *(float4*)&xs[row][c4 * 4] = v;
  }
#pragma unroll
  for (int i = 0; i < 8; ++i) {      // stage w tile: 128x64 int8
    int idx = tid + 256 * i;
    int k = idx >> 4, c4 = idx & 15;
    *(int*)&wsm[k][c4 * 4] = *(const int*)(w0q + (size_t)k * N + n0 + c4 * 4);
  }
  __syncthreads();
  const int ty = tid >> 4, tx = tid & 15;
  float acc[4][4] = {};
  for (int k4 = 0; k4 < K; k4 += 4) {
    float xr[4][4];
#pragma unroll
    for (int i = 0; i < 4; ++i) {
      float4 v = *(const float4*)&xs[ty * 4 + i][k4];
      xr[i][0] = v.x; xr[i][1] = v.y; xr[i][2] = v.z; xr[i][3] = v.w;
    }
#pragma unroll
    for (int kk = 0; kk < 4; ++kk) {
      char4 cv = *(const char4*)&wsm[k4 + kk][tx * 4];
      float w0 = (float)cv.x, w1 = (float)cv.y, w2 = (float)cv.z, w3 = (float)cv.w;
#pragma unroll
      for (int i = 0; i < 4; ++i) {
        acc[i][0] = fmaf(xr[i][kk], w0, acc[i][0]);
        acc[i][1] = fmaf(xr[i][kk], w1, acc[i][1]);
        acc[i][2] = fmaf(xr[i][kk], w2, acc[i][2]);
        acc[i][3] = fmaf(xr[i][kk], w3, acc[i][3]);
      }
    }
  }
  const int n = n0 + tx * 4;
  float b0v = 2.0f * bint[n + 0], b1v = 2.0f * bint[n + 1];
  float b2v = 2.0f * bint[n + 2], b3v = 2.0f * bint[n + 3];
#pragma unroll
  for (int i = 0; i < 4; ++i) {
    int m = m0 + ty * 4 + i;
    char4 o;
    o.x = qrelu_level(2.0f * acc[i][0] + b0v);
    o.y = qrelu_level(2.0f * acc[i][1] + b1v);
    o.z = qrelu_level(2.0f * acc[i][2] + b2v);
    o.w = qrelu_level(2.0f * acc[i][3] + b3v);
    *(char4*)&a1[(size_t)m * 1024 + n] = o;
  }
}

// ---------------------------------------------------------------- int8 GEMM
// C = A(MxK,int8) * BT(NxK,int8)^T.
//
// Round-11: LGKM-PIPELINED single-barrier schedule at the proven 256x256 /
// 8-wave / 3-buffer geometry (R2 = session best, 144 us).
//
// R7 post-mortem: __launch_bounds__(512,4) capped VGPR at 64 -> acc[8][4]
// (128 regs) spilled to scratch (VGPR_Count 64, WRITE 3.7 GB, MfmaUtil 4.6%).
// NEVER cap regs below the accumulator. 2 blocks/CU at 256^2 is infeasible
// (2x8 waves x ~190 regs > 512-reg file) -> R2's 1 block/CU is also
// register-bound, and the overlap must come from WITHIN the block.
//
// R2 model: per K-tile per CU: DS-read drain 1156 cyc + MFMA 1306 cyc run
// back-to-back (wall 2708) because lgkmcnt(0)+sched_barrier before each MFMA
// cluster makes every wave wait for ALL its reads. This round removes the
// pins: issue all 12 ds_reads + the 4 stage loads up front, then ONE
// setprio-wrapped 32-MFMA region. The compiler's dependency-tracked lgkmcnt
// (fine-grained, per m97 asm evidence) releases MFMA on af0/bf after ~8
// reads while af1 and other waves' reads are still being served -> DS pipe
// drains UNDER the MFMA clusters. Barriers: ONE per K-tile (publish buf
// t%3). Staging targets buf (t+2)%3, reads hit buf t%3 -> no intra-iter
// hazard; reads of buf (t-1)%3 are complete before each wave's barrier
// arrival (its MFMAs depend on them), so the stage overwrite is safe.
//
// vmcnt(4) discipline (unchanged from R2): at iter t end, outstanding =
// stage(t+1) 4 + stage(t+2) 4; wait-to-4 retires ALL of stage(t+1); next
// iter's barrier publishes it. Tail: vmcnt(0) at iter NT-2, none at NT-1.
//
// LDS bank-swizzle (kept, measured conflict-free): chunk kc of row `row`
// stored at position p = (kc + (row>>1)) & 3; fragment reads p = (quad+(r>>1))&3.
//
// FINAL=false: out int8 = clip(round(C/32 + 2*bint),0,63)   (relu-quant level)
// FINAL=true : out fp32 = C/2048 + bint/32
template <bool FINAL>
__global__ __launch_bounds__(512) void gemm_i8(const int8_t* __restrict__ A,
                                               const int8_t* __restrict__ BT,
                                               const float* __restrict__ bint,
                                               void* __restrict__ outp,
                                               int M, int N, int K) {
  __shared__ __align__(16) int8_t ldsA[3][256 * 64];
  __shared__ __align__(16) int8_t ldsB[3][256 * 64];
  const int tid = threadIdx.x;
  const int wid = tid >> 6;                 // 0..7
  const int lane = tid & 63;
  const int wm = wid >> 2, wn = wid & 3;    // 2 (M) x 4 (N) waves
  const int quad = lane >> 4, r = lane & 15;
  const int m0 = blockIdx.y * 256, n0 = blockIdx.x * 256;

  const int8_t* Ab = A + (size_t)m0 * K;
  const int8_t* Bb = BT + (size_t)n0 * K;

  // staging geometry (swizzled): thread covers LDS chunks tid and tid+512;
  // chunk c -> row = c>>2, pos p = c&3; fetch global chunk kc = (p-(row>>1))&3.
  const int srow = tid >> 2;                // 0..127 (second async: +128)
  const int sp = tid & 3;
  const int skc = (sp - (srow >> 1)) & 3;   // same for row+128
  const int8_t* gA0 = Ab + (size_t)srow * K + skc * 16;
  const int8_t* gA1 = Ab + (size_t)(srow + 128) * K + skc * 16;
  const int8_t* gB0 = Bb + (size_t)srow * K + skc * 16;
  const int8_t* gB1 = Bb + (size_t)(srow + 128) * K + skc * 16;
  const int ldsOff0 = (wid * 64) * 16;          // wave-uniform; HW adds lane*16
  const int ldsOff1 = (512 + wid * 64) * 16;

  // fragment-read position within a row's 64B
  const int pfrag = (quad + (r >> 1)) & 3;

  v4i acc[8][4] = {};

#define STAGE(buf, kt)                                \
  do {                                                \
    async16(gA0 + (kt) * 64, &ldsA[buf][ldsOff0]);    \
    async16(gA1 + (kt) * 64, &ldsA[buf][ldsOff1]);    \
    async16(gB0 + (kt) * 64, &ldsB[buf][ldsOff0]);    \
    async16(gB1 + (kt) * 64, &ldsB[buf][ldsOff1]);    \
  } while (0)

  // One K-tile: BAR -> issue 12 ds_reads + 4 stage loads -> 32 MFMA (compiler
  // inserts counted lgkm waits; DS serves later reads under earlier MFMAs)
  // -> counted vmcnt. doStage/vmN fold at expansion (4/0/-1).
#define ITER(p, q, kt, doStage, vmN)                                          \
  do {                                                                        \
    __builtin_amdgcn_s_barrier();                                             \
    v4i bf[4], af0[4], af1[4];                                                \
    const int8_t* La_ = &ldsA[p][0];                                          \
    const int8_t* Lb_ = &ldsB[p][0];                                          \
    _Pragma("unroll")                                                         \
    for (int nt = 0; nt < 4; ++nt)                                            \
      bf[nt] = *(const v4i*)&Lb_[(wn * 64 + nt * 16 + r) * 64 + pfrag * 16];  \
    _Pragma("unroll")                                                         \
    for (int mt = 0; mt < 4; ++mt)                                            \
      af0[mt] = *(const v4i*)&La_[(wm * 128 + mt * 16 + r) * 64 + pfrag * 16];\
    _Pragma("unroll")                                                         \
    for (int mt = 0; mt < 4; ++mt)                                            \
      af1[mt] = *(const v4i*)&La_[(wm * 128 + 64 + mt * 16 + r) * 64 +        \
                                  pfrag * 16];                                \
    if (doStage) STAGE(q, kt);                                                \
    __builtin_amdgcn_s_setprio(1);                                            \
    _Pragma("unroll")                                                         \
    for (int mt = 0; mt < 4; ++mt)                                            \
      _Pragma("unroll")                                                       \
      for (int nt = 0; nt < 4; ++nt)                                          \
        acc[mt][nt] = __builtin_amdgcn_mfma_i32_16x16x64_i8(                  \
            af0[mt], bf[nt], acc[mt][nt], 0, 0, 0);                           \
    _Pragma("unroll")                                                         \
    for (int mt = 0; mt < 4; ++mt)                                            \
      _Pragma("unroll")                                                       \
      for (int nt = 0; nt < 4; ++nt)                                          \
        acc[4 + mt][nt] = __builtin_amdgcn_mfma_i32_16x16x64_i8(              \
            af1[mt], bf[nt], acc[4 + mt][nt], 0, 0, 0);                       \
    __builtin_amdgcn_s_setprio(0);                                            \
    if (vmN == 4) asm volatile("s_waitcnt vmcnt(4)" ::: "memory");            \
    if (vmN == 0) asm volatile("s_waitcnt vmcnt(0)" ::: "memory");            \
  } while (0)

  const int NT = K >> 6;  // 16 / 32 / 64

  // prologue: stage tiles 0,1; retire tile 0 (tile 1's 4 loads stay in flight)
  STAGE(0, 0);
  STAGE(1, 1);
  asm volatile("s_waitcnt vmcnt(4)" ::: "memory");

  for (int t = 0; t < NT - 2; ++t) {
    ITER(t % 3, (t + 2) % 3, t + 2, true, 4);
  }
  ITER((NT - 2) % 3, 0, 0, false, 0);   // retires tile NT-1's stage loads
  ITER((NT - 1) % 3, 0, 0, false, -1);

#undef ITER
#undef STAGE

  const int mbase = m0 + wm * 128;
  const int nbase = n0 + wn * 64;
  if (FINAL) {
    float* out = (float*)outp;
#pragma unroll
    for (int nt = 0; nt < 4; ++nt) {
      int n = nbase + nt * 16 + r;
      float bq = bint[n] * 0.03125f;
#pragma unroll
      for (int mt = 0; mt < 8; ++mt)
#pragma unroll
        for (int g = 0; g < 4; ++g) {
          int m = mbase + mt * 16 + quad * 4 + g;
          out[(size_t)m * N + n] = (float)acc[mt][nt][g] * (1.0f / 2048.0f) + bq;
        }
    }
  } else {
    int8_t* out = (int8_t*)outp;
#pragma unroll
    for (int nt = 0; nt < 4; ++nt) {
      int n = nbase + nt * 16 + r;
      float b2 = 2.0f * bint[n];
#pragma unroll
      for (int mt = 0; mt < 8; ++mt)
#pragma unroll
        for (int g = 0; g < 4; ++g) {
          int m = mbase + mt * 16 + quad * 4 + g;
          // p = C/32 + 2*bint exactly representable in fp32 -> exact half-even ties
          out[(size_t)m * N + n] =
              qrelu_level((float)acc[mt][nt][g] * 0.03125f + b2);
        }
    }
  }
}

// ---------------------------------------------------------------- launch
extern "C" void kernel_launch(void* const* d_in, const int* in_sizes, int n_in,
                              void* d_out, int out_size, void* d_ws, size_t ws_size,
                              hipStream_t stream) {
  const float* x  = (const float*)d_in[0];
  const float* W0 = (const float*)d_in[1];
  const float* b0 = (const float*)d_in[2];
  const float* W1 = (const float*)d_in[3];
  const float* b1 = (const float*)d_in[4];
  const float* W2 = (const float*)d_in[5];
  const float* b2 = (const float*)d_in[6];
  const float* W3 = (const float*)d_in[7];
  const float* b3 = (const float*)d_in[8];

  uint8_t* ws = (uint8_t*)d_ws;
  int8_t* wq0 = (int8_t*)(ws + 0);          // 128x1024 int8   (K-major)
  int8_t* wt1 = (int8_t*)(ws + 131072);     // 2048x1024 int8  (N x K)
  int8_t* wt2 = (int8_t*)(ws + 2228224);    // 4096x2048
  int8_t* wt3 = (int8_t*)(ws + 10616832);   // 4096x4096
  float*  bq0 = (float*)(ws + 27394048);    // 1024 f32 (integer levels)
  float*  bq1 = (float*)(ws + 27398144);    // 2048
  float*  bq2 = (float*)(ws + 27406336);    // 4096
  float*  bq3 = (float*)(ws + 27422720);    // 4096
  int8_t* a1  = (int8_t*)(ws + 27439104);   // 8192x1024 int8
  int8_t* a2  = (int8_t*)(ws + 35827712);   // 8192x2048
  int8_t* a3  = (int8_t*)(ws + 52604928);   // 8192x4096  (ends at 86159360 B)

  quant_w0_k<<<128, 256, 0, stream>>>(W0, wq0);
  quantT_k<<<dim3(2048 / 64, 1024 / 64), 256, 0, stream>>>(W1, wt1, 1024, 2048);
  quantT_k<<<dim3(4096 / 64, 2048 / 64), 256, 0, stream>>>(W2, wt2, 2048, 4096);
  quantT_k<<<dim3(4096 / 64, 4096 / 64), 256, 0, stream>>>(W3, wt3, 4096, 4096);
  quant_bias_k<<<16, 256, 0, stream>>>(b0, b1, b2, b3, bq0, bq1, bq2, bq3);
  layer0_k<<<dim3(16, 128), 256, 0, stream>>>(x, wq0, bq0, a1);
  gemm_i8<false><<<dim3(2048 / 256, 8192 / 256), 512, 0, stream>>>(
      a1, wt1, bq1, a2, 8192, 2048, 1024);
  gemm_i8<false><<<dim3(4096 / 256, 8192 / 256), 512, 0, stream>>>(
      a2, wt2, bq2, a3, 8192, 4096, 2048);
  gemm_i8<true><<<dim3(4096 / 256, 8192 / 256), 512, 0, stream>>>(
      a3, wt3, bq3, d_out, 8192, 4096, 4096);
}